// Round 11
// baseline (893.441 us; speedup 1.0000x reference)
//
#include <hip/hip_runtime.h>

#define S_LEN 1024
#define BATCH 4096
#define NIN 64
#define NHID 128
#define BT 16      // batch rows per block (one h-chain per block)

typedef __attribute__((ext_vector_type(8))) short bf16x8;
typedef __attribute__((ext_vector_type(4))) float f32x4;

__device__ __forceinline__ unsigned cvt_pk(float lo, float hi) {
    unsigned r;
    asm("v_cvt_pk_bf16_f32 %0, %1, %2" : "=v"(r) : "v"(lo), "v"(hi));
    return r;
}
__device__ __forceinline__ float tanh_fast(float z) {
    // tanh(z) = 1 - 2/(e^{2z}+1)
    float u = __builtin_amdgcn_exp2f(z * 2.885390081777927f);
    return fmaf(-2.0f, __builtin_amdgcn_rcpf(u + 1.0f), 1.0f);
}
// barrier without vmcnt drain (x prefetch loads stay in flight)
__device__ __forceinline__ void lds_barrier() {
    asm volatile("s_waitcnt lgkmcnt(0)\n\ts_barrier" ::: "memory");
    __builtin_amdgcn_sched_barrier(0);
}

#define MFMA __builtin_amdgcn_mfma_f32_16x16x32_bf16

__device__ __forceinline__ bf16x8 pack8(const f32x4& a, const f32x4& b) {
    union { bf16x8 v; unsigned u[4]; } r;
    r.u[0] = cvt_pk(a[0], a[1]); r.u[1] = cvt_pk(a[2], a[3]);
    r.u[2] = cvt_pk(b[0], b[1]); r.u[3] = cvt_pk(b[2], b[3]);
    return r.v;
}

// 8 waves (2/SIMD), wave w owns h rows [16w, 16w+16).
// Permuted-k (verified R6-R9): B-slot (kk,kg,j) carries logical hidden index
// m = 32kk + 16*(j>>2) + 4kg + (j&3). Wave w's acc (n = 16w+4kg+i) packs
// same-lane into the (w&1)-half (j<4 / j>=4) of B-slot kk = w>>1.
// LDS B-exchange: 2 bufs x [kk(4)][lane*16B], halves interleaved at +8*(w&1)
// so reads stay single b128 per slot. Write = b64 (one per wave, ~4-way).

__global__ __launch_bounds__(512, 2)
void rnn_kernel(const float* __restrict__ x,
                const float* __restrict__ W_ih,
                const float* __restrict__ b_ih,
                const float* __restrict__ W_hh,
                const float* __restrict__ b_hh,
                float* __restrict__ out)
{
    __shared__ __align__(16) char lds[8192];
    const int tid  = threadIdx.x;
    const int wv   = tid >> 6;        // 0..7, two waves per SIMD, uniform code
    const int lane = tid & 63;
    const int col  = lane & 15;
    const int kg   = lane >> 4;
    const int bb0  = blockIdx.x * BT;

    // zero B exchange (h_0 = 0)
    for (int i = tid; i < 2048; i += 512) ((int*)lds)[i] = 0;

    const int OWN = wv;               // runtime-uniform; addresses only
    char* lbx = lds + (lane << 4);
    char* wp  = lbx + ((OWN >> 1) << 10) + ((OWN & 1) << 3);  // own half-write
    const char* rp0 = lbx;                                     // B slot reads
    const char* rp1 = lbx + (1 << 10);
    const char* rp2 = lbx + (2 << 10);
    const char* rp3 = lbx + (3 << 10);

    // ---- persistent weights for n-rows [16*OWN, 16*OWN+16)
    // whh[q]: A-frag, k-tile q, columns permuted per mapping above
    bf16x8 whh0, whh1, whh2, whh3;
    {
        const float* rowp = W_hh + (size_t)(16 * OWN + col) * NHID + 4 * kg;
        #pragma unroll
        for (int q = 0; q < 4; ++q) {
            const float* pw = rowp + 32 * q;
            f32x4 c0 = *(const f32x4*)(pw);        // j = 0..3
            f32x4 c1 = *(const f32x4*)(pw + 16);   // j = 4..7
            bf16x8 fr = pack8(c0, c1);
            if (q == 0) whh0 = fr; else if (q == 1) whh1 = fr;
            else if (q == 2) whh2 = fr; else whh3 = fr;
        }
    }
    bf16x8 wihA, wihB;                 // natural k (x side unpermuted)
    {
        const float* q0 = W_ih + (size_t)(16 * OWN + col) * NIN + 8 * kg;
        wihA = pack8(*(const f32x4*)(q0),      *(const f32x4*)(q0 + 4));
        wihB = pack8(*(const f32x4*)(q0 + 32), *(const f32x4*)(q0 + 36));
    }
    f32x4 biasv;
    {
        f32x4 bi = *(const f32x4*)(b_ih + 16 * OWN + 4 * kg);
        f32x4 bh = *(const f32x4*)(b_hh + 16 * OWN + 4 * kg);
        biasv = bi + bh;
    }

    const float* xlane = x + ((size_t)bb0 + col) * NIN + kg * 8;
    auto loadStage = [&](f32x4& v0, f32x4& v1, f32x4& v2, f32x4& v3, int t) {
        if (t < S_LEN) {
            const float* p = xlane + (size_t)t * (BATCH * NIN);
            v0 = *(const f32x4*)(p);      v1 = *(const f32x4*)(p + 4);
            v2 = *(const f32x4*)(p + 32); v3 = *(const f32x4*)(p + 36);
        }
    };
    auto computeXP = [&](const f32x4& v0, const f32x4& v1,
                         const f32x4& v2, const f32x4& v3, f32x4& o0) {
        union { bf16x8 v; unsigned u[4]; } xa, xb;
        xa.u[0] = cvt_pk(v0[0], v0[1]); xa.u[1] = cvt_pk(v0[2], v0[3]);
        xa.u[2] = cvt_pk(v1[0], v1[1]); xa.u[3] = cvt_pk(v1[2], v1[3]);
        xb.u[0] = cvt_pk(v2[0], v2[1]); xb.u[1] = cvt_pk(v2[2], v2[3]);
        xb.u[2] = cvt_pk(v3[0], v3[1]); xb.u[3] = cvt_pk(v3[2], v3[3]);
        f32x4 p0 = biasv;
        p0 = MFMA(wihA, xa.v, p0, 0, 0, 0);
        p0 = MFMA(wihB, xb.v, p0, 0, 0, 0);
        o0 = p0;
    };

    // ---- prologue: stages <- x(0..3); xp(0); refill stage0 <- x(4)
    f32x4 S00, S01, S02, S03, S10, S11, S12, S13;
    f32x4 S20, S21, S22, S23, S30, S31, S32, S33;
    loadStage(S00, S01, S02, S03, 0);
    loadStage(S10, S11, S12, S13, 1);
    loadStage(S20, S21, S22, S23, 2);
    loadStage(S30, S31, S32, S33, 3);
    f32x4 xc, xn;
    computeXP(S00, S01, S02, S03, xc);
    loadStage(S00, S01, S02, S03, 4);
    __syncthreads();                            // B-zeros visible

    auto cstep = [&](int t, f32x4& s0, f32x4& s1, f32x4& s2, f32x4& s3,
                     const f32x4& c, f32x4& n, bool last) {
        // B reads first; latency covered by xp/cvt issue below
        const int rb = (t & 1) << 12;
        bf16x8 B0 = *(const bf16x8*)(rp0 + rb);
        bf16x8 B1 = *(const bf16x8*)(rp1 + rb);
        bf16x8 B2 = *(const bf16x8*)(rp2 + rb);
        bf16x8 B3 = *(const bf16x8*)(rp3 + rb);

        computeXP(s0, s1, s2, s3, n);        // xp(t+1): independent issue
        loadStage(s0, s1, s2, s3, t + 5);    // refill (consumed at t+4)

        // depth-2 MFMA tree
        f32x4 c0 = c;
        const f32x4 z4 = {0.f, 0.f, 0.f, 0.f};
        f32x4 c1 = z4;
        c0 = MFMA(whh0, B0, c0, 0, 0, 0);
        c1 = MFMA(whh2, B2, c1, 0, 0, 0);
        c0 = MFMA(whh1, B1, c0, 0, 0, 0);
        c1 = MFMA(whh3, B3, c1, 0, 0, 0);
        f32x4 pre = c0 + c1;

        f32x4 v;
        #pragma unroll
        for (int i = 0; i < 4; ++i) v[i] = tanh_fast(pre[i]);

        if (last) {
            *(f32x4*)(out + ((size_t)bb0 + col) * NHID + 16 * OWN + 4 * kg) = v;
        } else {
            uint2 hb;
            hb.x = cvt_pk(v[0], v[1]);
            hb.y = cvt_pk(v[2], v[3]);
            *(uint2*)(wp + (((t + 1) & 1) << 12)) = hb;   // own half, b64
        }
        lds_barrier();
    };

    for (int m = 0; m < 255; ++m) {
        const int t = 4 * m;
        cstep(t + 0, S10, S11, S12, S13, xc, xn, false);
        cstep(t + 1, S20, S21, S22, S23, xn, xc, false);
        cstep(t + 2, S30, S31, S32, S33, xc, xn, false);
        cstep(t + 3, S00, S01, S02, S03, xn, xc, false);
    }
    cstep(1020, S10, S11, S12, S13, xc, xn, false);
    cstep(1021, S20, S21, S22, S23, xn, xc, false);
    cstep(1022, S30, S31, S32, S33, xc, xn, false);
    cstep(1023, S00, S01, S02, S03, xn, xc, true);
}

extern "C" void kernel_launch(void* const* d_in, const int* in_sizes, int n_in,
                              void* d_out, int out_size, void* d_ws, size_t ws_size,
                              hipStream_t stream) {
    const float* x    = (const float*)d_in[0];
    const float* W_ih = (const float*)d_in[1];
    const float* b_ih = (const float*)d_in[2];
    const float* W_hh = (const float*)d_in[3];
    const float* b_hh = (const float*)d_in[4];
    float* out = (float*)d_out;

    dim3 grid(BATCH / BT);
    dim3 block(512);
    rnn_kernel<<<grid, block, 0, stream>>>(x, W_ih, b_ih, W_hh, b_hh, out);
}

// Round 12
// 480.167 us; speedup vs baseline: 1.8607x; 1.8607x over previous
//
#include <hip/hip_runtime.h>

#define S_LEN 1024
#define BATCH 4096
#define NIN 64
#define NHID 128
#define BT 16      // batch rows per block (one h-chain per block)

typedef __attribute__((ext_vector_type(8))) short bf16x8;
typedef __attribute__((ext_vector_type(4))) float f32x4;

__device__ __forceinline__ unsigned cvt_pk(float lo, float hi) {
    unsigned r;
    asm("v_cvt_pk_bf16_f32 %0, %1, %2" : "=v"(r) : "v"(lo), "v"(hi));
    return r;
}
__device__ __forceinline__ float tanh_fast(float z) {
    // tanh(z) = 1 - 2/(e^{2z}+1)
    float u = __builtin_amdgcn_exp2f(z * 2.885390081777927f);
    return fmaf(-2.0f, __builtin_amdgcn_rcpf(u + 1.0f), 1.0f);
}
// barrier without vmcnt drain (x prefetch loads stay in flight).
// "memory" clobber orders LDS/global ops; no sched_barrier (reads are
// compiler-tracked C++ derefs, and we WANT cross-barrier reg scheduling).
__device__ __forceinline__ void lds_barrier() {
    asm volatile("s_waitcnt lgkmcnt(0)\n\ts_barrier" ::: "memory");
}

#define MFMA __builtin_amdgcn_mfma_f32_16x16x32_bf16

__device__ __forceinline__ bf16x8 pack8(const f32x4& a, const f32x4& b) {
    union { bf16x8 v; unsigned u[4]; } r;
    r.u[0] = cvt_pk(a[0], a[1]); r.u[1] = cvt_pk(a[2], a[3]);
    r.u[2] = cvt_pk(b[0], b[1]); r.u[3] = cvt_pk(b[2], b[3]);
    return r.v;
}

// Permuted-k (verified R6-R9): B-slot (kk,kg,j) carries logical hidden index
// m = 32kk + 16*(j>>2) + 4kg + (j&3). Wave OWN (=wv) owns tt {2*OWN, 2*OWN+1}:
// its accs pack same-lane into B-slot OWN (j<4 half = tt0, j>=4 half = tt1);
// own slot stays in registers, 3 partner slots cross LDS.
// LDS: 2 bufs x 4KB: buf b at b<<12, slot kk at kk<<10, lane<<4.

__global__ __launch_bounds__(256, 1)
void rnn_kernel(const float* __restrict__ x,
                const float* __restrict__ W_ih,
                const float* __restrict__ b_ih,
                const float* __restrict__ W_hh,
                const float* __restrict__ b_hh,
                float* __restrict__ out)
{
    __shared__ __align__(16) char lds[8192];
    const int tid  = threadIdx.x;
    const int wv   = tid >> 6;        // 0..3 — one wave per SIMD, uniform code
    const int lane = tid & 63;
    const int col  = lane & 15;
    const int kg   = lane >> 4;
    const int bb0  = blockIdx.x * BT;

    // zero B exchange (h_0 = 0)
    for (int i = tid; i < 2048; i += 256) ((int*)lds)[i] = 0;

    const int OWN = wv;               // runtime-uniform; addresses only
    char* lbx = lds + (lane << 4);
    char*       wp  = lbx + (OWN << 10);
    const char* rp1 = lbx + ((((OWN + 1) & 3)) << 10);
    const char* rp2 = lbx + ((((OWN + 2) & 3)) << 10);
    const char* rp3 = lbx + ((((OWN + 3) & 3)) << 10);

    // ---- persistent weights for tt0 = 2*OWN, tt1 = 2*OWN+1
    // whh0/whh1[q]: W_hh column-slice kk = (OWN+q)&3 (register index q: STATIC)
    bf16x8 whh0[4], whh1[4];
    const int tt0 = 2 * OWN, tt1 = tt0 + 1;
    #pragma unroll
    for (int q = 0; q < 4; ++q) {
        const int kkq = (OWN + q) & 3;                 // runtime-uniform addr
        {
            const float* pw = W_hh + (16 * tt0 + col) * NHID + 32 * kkq + 4 * kg;
            whh0[q] = pack8(*(const f32x4*)(pw), *(const f32x4*)(pw + 16));
        }
        {
            const float* pw = W_hh + (16 * tt1 + col) * NHID + 32 * kkq + 4 * kg;
            whh1[q] = pack8(*(const f32x4*)(pw), *(const f32x4*)(pw + 16));
        }
    }
    bf16x8 wihA0, wihB0, wihA1, wihB1;   // natural k (x side unpermuted)
    {
        const float* q0 = W_ih + (16 * tt0 + col) * NIN + 8 * kg;
        const float* q1 = W_ih + (16 * tt1 + col) * NIN + 8 * kg;
        wihA0 = pack8(*(const f32x4*)(q0),      *(const f32x4*)(q0 + 4));
        wihB0 = pack8(*(const f32x4*)(q0 + 32), *(const f32x4*)(q0 + 36));
        wihA1 = pack8(*(const f32x4*)(q1),      *(const f32x4*)(q1 + 4));
        wihB1 = pack8(*(const f32x4*)(q1 + 32), *(const f32x4*)(q1 + 36));
    }
    f32x4 bias0, bias1;
    {
        f32x4 bi = *(const f32x4*)(b_ih + 16 * tt0 + 4 * kg);
        f32x4 bh = *(const f32x4*)(b_hh + 16 * tt0 + 4 * kg);
        bias0 = bi + bh;
        bi = *(const f32x4*)(b_ih + 16 * tt1 + 4 * kg);
        bh = *(const f32x4*)(b_hh + 16 * tt1 + 4 * kg);
        bias1 = bi + bh;
    }

    const float* xlane = x + ((size_t)bb0 + col) * NIN + kg * 8;

    auto loadStage = [&](f32x4& v0, f32x4& v1, f32x4& v2, f32x4& v3, int t) {
        if (t < S_LEN) {
            const float* p = xlane + (size_t)t * (BATCH * NIN);
            v0 = *(const f32x4*)(p);      v1 = *(const f32x4*)(p + 4);
            v2 = *(const f32x4*)(p + 32); v3 = *(const f32x4*)(p + 36);
        }
    };
    auto computeXP = [&](const f32x4& v0, const f32x4& v1,
                         const f32x4& v2, const f32x4& v3,
                         f32x4& o0, f32x4& o1) {
        union { bf16x8 v; unsigned u[4]; } xa, xb;
        xa.u[0] = cvt_pk(v0[0], v0[1]); xa.u[1] = cvt_pk(v0[2], v0[3]);
        xa.u[2] = cvt_pk(v1[0], v1[1]); xa.u[3] = cvt_pk(v1[2], v1[3]);
        xb.u[0] = cvt_pk(v2[0], v2[1]); xb.u[1] = cvt_pk(v2[2], v2[3]);
        xb.u[2] = cvt_pk(v3[0], v3[1]); xb.u[3] = cvt_pk(v3[2], v3[3]);
        f32x4 p0 = bias0, p1 = bias1;
        p0 = MFMA(wihA0, xa.v, p0, 0, 0, 0);
        p1 = MFMA(wihA1, xa.v, p1, 0, 0, 0);
        p0 = MFMA(wihB0, xb.v, p0, 0, 0, 0);
        p1 = MFMA(wihB1, xb.v, p1, 0, 0, 0);
        o0 = p0; o1 = p1;
    };

    // ---- prologue: stages <- x(0..3); xp(0); refill stage0 <- x(4)
    f32x4 S00, S01, S02, S03, S10, S11, S12, S13;
    f32x4 S20, S21, S22, S23, S30, S31, S32, S33;
    loadStage(S00, S01, S02, S03, 0);
    loadStage(S10, S11, S12, S13, 1);
    loadStage(S20, S21, S22, S23, 2);
    loadStage(S30, S31, S32, S33, 3);
    f32x4 xc0, xc1, xn0, xn1;
    computeXP(S00, S01, S02, S03, xc0, xc1);
    loadStage(S00, S01, S02, S03, 4);
    bf16x8 Bo = {0, 0, 0, 0, 0, 0, 0, 0};       // own slice of h(0) = 0
    __syncthreads();                            // B-zeros visible

    auto cstep = [&](int t, f32x4& s0, f32x4& s1, f32x4& s2, f32x4& s3,
                     const f32x4& c0, const f32x4& c1,
                     f32x4& n0, f32x4& n1, bool last) {
        // partner B reads issue first; latency covered by own-MFMA + xp block
        const int rb = (t & 1) << 12;
        bf16x8 P1 = *(const bf16x8*)(rp1 + rb);
        bf16x8 P2 = *(const bf16x8*)(rp2 + rb);
        bf16x8 P3 = *(const bf16x8*)(rp3 + rb);

        f32x4 a0 = c0, a1 = c1;
        a0 = MFMA(whh0[0], Bo, a0, 0, 0, 0);     // own slot: no LDS wait
        a1 = MFMA(whh1[0], Bo, a1, 0, 0, 0);

        computeXP(s0, s1, s2, s3, n0, n1);       // xp(t+1): independent issue
        loadStage(s0, s1, s2, s3, t + 5);        // refill (consumed at t+4)

        a0 = MFMA(whh0[1], P1, a0, 0, 0, 0);
        a1 = MFMA(whh1[1], P1, a1, 0, 0, 0);
        a0 = MFMA(whh0[2], P2, a0, 0, 0, 0);
        a1 = MFMA(whh1[2], P2, a1, 0, 0, 0);
        a0 = MFMA(whh0[3], P3, a0, 0, 0, 0);
        a1 = MFMA(whh1[3], P3, a1, 0, 0, 0);

        if (last) {
            #pragma unroll
            for (int i = 0; i < 4; ++i) a0[i] = tanh_fast(a0[i]);
            #pragma unroll
            for (int i = 0; i < 4; ++i) a1[i] = tanh_fast(a1[i]);
            float* ob = out + ((size_t)bb0 + col) * NHID + 32 * OWN + 4 * kg;
            *(f32x4*)(ob)      = a0;
            *(f32x4*)(ob + 16) = a1;
            lds_barrier();
            return;
        }
        // tt0: tanh -> pack -> write its b64 half EARLY (overlaps tt1 tanh)
        #pragma unroll
        for (int i = 0; i < 4; ++i) a0[i] = tanh_fast(a0[i]);
        unsigned u0 = cvt_pk(a0[0], a0[1]);
        unsigned u1 = cvt_pk(a0[2], a0[3]);
        uint2 h0; h0.x = u0; h0.y = u1;
        char* wb = wp + (((t + 1) & 1) << 12);
        *(uint2*)(wb) = h0;                      // ds_write_b64 half 1
        // tt1: tanh -> pack -> write second half
        #pragma unroll
        for (int i = 0; i < 4; ++i) a1[i] = tanh_fast(a1[i]);
        unsigned u2 = cvt_pk(a1[0], a1[1]);
        unsigned u3 = cvt_pk(a1[2], a1[3]);
        uint2 h1; h1.x = u2; h1.y = u3;
        *(uint2*)(wb + 8) = h1;                  // ds_write_b64 half 2
        // rebuild own B-frag in regs (no LDS read of own slot)
        union { bf16x8 v; unsigned u[4]; } fb;
        fb.u[0] = u0; fb.u[1] = u1; fb.u[2] = u2; fb.u[3] = u3;
        Bo = fb.v;
        lds_barrier();
    };

    for (int m = 0; m < 255; ++m) {
        const int t = 4 * m;
        cstep(t + 0, S10, S11, S12, S13, xc0, xc1, xn0, xn1, false);
        cstep(t + 1, S20, S21, S22, S23, xn0, xn1, xc0, xc1, false);
        cstep(t + 2, S30, S31, S32, S33, xc0, xc1, xn0, xn1, false);
        cstep(t + 3, S00, S01, S02, S03, xn0, xn1, xc0, xc1, false);
    }
    cstep(1020, S10, S11, S12, S13, xc0, xc1, xn0, xn1, false);
    cstep(1021, S20, S21, S22, S23, xn0, xn1, xc0, xc1, false);
    cstep(1022, S30, S31, S32, S33, xc0, xc1, xn0, xn1, false);
    cstep(1023, S00, S01, S02, S03, xn0, xn1, xc0, xc1, true);
}

extern "C" void kernel_launch(void* const* d_in, const int* in_sizes, int n_in,
                              void* d_out, int out_size, void* d_ws, size_t ws_size,
                              hipStream_t stream) {
    const float* x    = (const float*)d_in[0];
    const float* W_ih = (const float*)d_in[1];
    const float* b_ih = (const float*)d_in[2];
    const float* W_hh = (const float*)d_in[3];
    const float* b_hh = (const float*)d_in[4];
    float* out = (float*)d_out;

    dim3 grid(BATCH / BT);
    dim3 block(256);
    rnn_kernel<<<grid, block, 0, stream>>>(x, W_ih, b_ih, W_hh, b_hh, out);
}